// Round 16
// baseline (632.067 us; speedup 1.0000x reference)
//
#include <hip/hip_runtime.h>
#include <hip/hip_bf16.h>

// GNN decoder: 2x (GCNConv -> BatchNorm[-> ReLU]) on N=100000 nodes, E=1.6M edges.
// Round 16: r15's grid-barrier was a spin-on-RMW bug (1024 blocks polling
// atomicAdd(ctr,0) -> ~100us/barrier of RMW serialization on one line). Fix:
// poll with relaxed device-scope ATOMIC LOAD (concurrent, no ownership) +
// s_sleep(16) backoff + acquire fence. Everything else identical to r15
// (= r13 kernels + preproc/gemm1 consolidation, 8 dispatches).
// Carries: 64-slab 1024-block stats (r13), bucketed two-phase CSR build (r10),
// one-wave-per-node aggregates at ~3.8TB/s L3-fabric gather floor (r5/r13),
// dinv-prescaled GEMMs (r4), bf16 intermediates + no-LDS MFMA GEMMs (r3),
// CSR gather (r2), BN bias cancellation (r1).

#define IN_C 128
#define HID_C 128
#define OUT_C2 64
#define BN_EPS 1e-5f
#define NB_STATS 1024
#define NSLAB 64
#define NB_PRE 1024

typedef __attribute__((ext_vector_type(8))) short short8v;
typedef __attribute__((ext_vector_type(4))) float float4v;
typedef __attribute__((ext_vector_type(4))) int int4v;

__device__ inline ushort f2bf(float f) {
    union { float f; unsigned u; } x; x.f = f;
    return (ushort)((x.u + 0x7fffu + ((x.u >> 16) & 1u)) >> 16);  // RNE
}
__device__ inline float bf2f(ushort u) {
    union { unsigned u; float f; } x; x.u = ((unsigned)u) << 16;
    return x.f;
}

// co-resident spin grid-barrier: RMW arrive, ATOMIC-LOAD poll (fix for r15)
__device__ inline void gbar(int* ctr, int target) {
    __syncthreads();
    if (threadIdx.x == 0) {
        __threadfence();                                   // release
        atomicAdd(ctr, 1);
        while (__hip_atomic_load(ctr, __ATOMIC_RELAXED,
                                 __HIP_MEMORY_SCOPE_AGENT) < target)
            __builtin_amdgcn_s_sleep(16);
        __threadfence();                                   // acquire
    }
    __syncthreads();
}

// W[128][OC] f32 -> fragment-ordered bf16
template <int OC>
__device__ inline void wreorder_impl(const float* __restrict__ W,
                                     ushort* __restrict__ wfrag, int t) {
    constexpr int NCT = OC / 16;
    int lane = t & 63;
    int rest = t >> 6;
    int ct = rest % NCT;
    int kk = rest / NCT;
    int col = ct * 16 + (lane & 15);
    int krow = kk * 32 + (lane >> 4) * 8;
    ushort tmp[8];
    #pragma unroll
    for (int e = 0; e < 8; ++e)
        tmp[e] = f2bf(W[(size_t)(krow + e) * OC + col]);
    uint4 st;
    st.x = (uint)tmp[0] | ((uint)tmp[1] << 16);
    st.y = (uint)tmp[2] | ((uint)tmp[3] << 16);
    st.z = (uint)tmp[4] | ((uint)tmp[5] << 16);
    st.w = (uint)tmp[6] | ((uint)tmp[7] << 16);
    *(uint4*)&wfrag[(size_t)t * 8] = st;
}

// MFMA GEMM body: Y[N][OC] bf16 = dinv[row] * (A @ W). No LDS. NT f32 A loads.
template <int OC, bool BN_IN>
__device__ inline void gemm_body(
    const void* __restrict__ Xv, const ushort* __restrict__ wfrag,
    ushort* __restrict__ Y, const float* __restrict__ dinv,
    const float* __restrict__ sc, const float* __restrict__ sh,
    int N, int wave, int lane)
{
    constexpr int NCT = OC / 16;
    int row16 = wave * 16;
    if (row16 >= N) return;
    int r = lane & 15;
    int g = lane >> 4;
    int row = row16 + r;

    float4v acc[NCT];
    #pragma unroll
    for (int ct = 0; ct < NCT; ++ct) acc[ct] = (float4v){0.f, 0.f, 0.f, 0.f};

    const short8v* wf = (const short8v*)wfrag;

    #pragma unroll
    for (int kk = 0; kk < 4; ++kk) {
        int k0 = kk * 32 + g * 8;
        short8v a;
        if constexpr (!BN_IN) {
            const float* xp = (const float*)Xv + (size_t)row * 128 + k0;
            float4v x0 = __builtin_nontemporal_load((const float4v*)xp);
            float4v x1 = __builtin_nontemporal_load((const float4v*)(xp + 4));
            a[0] = (short)f2bf(x0[0]); a[1] = (short)f2bf(x0[1]);
            a[2] = (short)f2bf(x0[2]); a[3] = (short)f2bf(x0[3]);
            a[4] = (short)f2bf(x1[0]); a[5] = (short)f2bf(x1[1]);
            a[6] = (short)f2bf(x1[2]); a[7] = (short)f2bf(x1[3]);
        } else {
            const ushort* xp = (const ushort*)Xv + (size_t)row * 128 + k0;
            uint4 v = *(const uint4*)xp;
            float4 s0 = *(const float4*)&sc[k0];
            float4 s1 = *(const float4*)&sc[k0 + 4];
            float4 h0 = *(const float4*)&sh[k0];
            float4 h1 = *(const float4*)&sh[k0 + 4];
            a[0] = (short)f2bf(fmaxf(fmaf(bf2f((ushort)(v.x & 0xffff)), s0.x, h0.x), 0.f));
            a[1] = (short)f2bf(fmaxf(fmaf(bf2f((ushort)(v.x >> 16)),    s0.y, h0.y), 0.f));
            a[2] = (short)f2bf(fmaxf(fmaf(bf2f((ushort)(v.y & 0xffff)), s0.z, h0.z), 0.f));
            a[3] = (short)f2bf(fmaxf(fmaf(bf2f((ushort)(v.y >> 16)),    s0.w, h0.w), 0.f));
            a[4] = (short)f2bf(fmaxf(fmaf(bf2f((ushort)(v.z & 0xffff)), s1.x, h1.x), 0.f));
            a[5] = (short)f2bf(fmaxf(fmaf(bf2f((ushort)(v.z >> 16)),    s1.y, h1.y), 0.f));
            a[6] = (short)f2bf(fmaxf(fmaf(bf2f((ushort)(v.w & 0xffff)), s1.z, h1.z), 0.f));
            a[7] = (short)f2bf(fmaxf(fmaf(bf2f((ushort)(v.w >> 16)),    s1.w, h1.w), 0.f));
        }
        #pragma unroll
        for (int ct = 0; ct < NCT; ++ct) {
            short8v b = wf[((size_t)(kk * NCT + ct)) * 64 + lane];
            acc[ct] = __builtin_amdgcn_mfma_f32_16x16x32_bf16(a, b, acc[ct], 0, 0, 0);
        }
    }
    float di[4];
    #pragma unroll
    for (int i = 0; i < 4; ++i) di[i] = dinv[row16 + g * 4 + i];
    #pragma unroll
    for (int ct = 0; ct < NCT; ++ct) {
        #pragma unroll
        for (int i = 0; i < 4; ++i) {
            int orow = row16 + g * 4 + i;
            Y[(size_t)orow * OC + ct * 16 + r] = f2bf(acc[ct][i] * di[i]);
        }
    }
}

// Consolidated: wreorder + bucket count -> B1 -> scan+scatter -> B2 ->
// per-bucket CSR -> B3 -> GEMM1. 1024 co-resident blocks, spin barriers.
__global__ __launch_bounds__(256, 4) void preproc_gemm1_kernel(
    const int* __restrict__ src, const int* __restrict__ dst,
    int* __restrict__ bcnt, int* __restrict__ bcursor, int2* __restrict__ pairs,
    int* __restrict__ csr_src, int* __restrict__ row_ptr, float* __restrict__ dinv,
    int* __restrict__ bar,
    const float* __restrict__ W1, const float* __restrict__ W2,
    ushort* __restrict__ wf1, ushort* __restrict__ wf2,
    const float* __restrict__ x, ushort* __restrict__ h1,
    int E, int N, int nTiles, int nbuck, int nbGemm)
{
    __shared__ int smem[1536];  // 6KB, aliased per phase
    int t = threadIdx.x;

    // ---- Phase A: weight reorder (blocks 0-11) + bucket histogram ----
    if (blockIdx.x < 12) {
        if (blockIdx.x < 8) wreorder_impl<HID_C>(W1, wf1, blockIdx.x * 256 + t);
        else                wreorder_impl<OUT_C2>(W2, wf2, (blockIdx.x - 8) * 256 + t);
    }
    {
        int* h = smem;
        h[t] = 0; h[t + 256] = 0;
        __syncthreads();
        for (int tile = blockIdx.x; tile < nTiles; tile += NB_PRE) {
            int i0 = tile * 1024 + t * 4;
            if (i0 < E) {  // E % 4 == 0
                int4v d = __builtin_nontemporal_load((const int4v*)&dst[i0]);
                atomicAdd(&h[d.x >> 8], 1);
                atomicAdd(&h[d.y >> 8], 1);
                atomicAdd(&h[d.z >> 8], 1);
                atomicAdd(&h[d.w >> 8], 1);
            }
        }
        __syncthreads();
        if (h[t])       atomicAdd(&bcnt[t], h[t]);
        if (h[t + 256]) atomicAdd(&bcnt[t + 256], h[t + 256]);
    }
    gbar(&bar[0], NB_PRE);

    // ---- Phase B: exclusive scan of bcnt (per-block, LDS) + scatter ----
    {
        int* bs = smem;
        int* h  = smem + 512;
        int* gb = smem + 1024;
        int a = bcnt[t], b = bcnt[t + 256];
        bs[t] = a; bs[t + 256] = b;
        __syncthreads();
        for (int off = 1; off < 512; off <<= 1) {
            int v0 = (t >= off) ? bs[t - off] : 0;
            int v1 = bs[t + 256 - off];
            __syncthreads();
            bs[t] += v0; bs[t + 256] += v1;
            __syncthreads();
        }
        int e0 = bs[t] - a, e1 = bs[t + 256] - b;
        __syncthreads();
        bs[t] = e0; bs[t + 256] = e1;
        __syncthreads();
        for (int tile = blockIdx.x; tile < nTiles; tile += NB_PRE) {
            h[t] = 0; h[t + 256] = 0;
            __syncthreads();
            int i0 = tile * 1024 + t * 4;
            bool act = i0 < E;
            int4v d, s;
            int bk0 = 0, bk1 = 0, bk2 = 0, bk3 = 0, r0 = 0, r1 = 0, r2 = 0, r3 = 0;
            if (act) {
                d = __builtin_nontemporal_load((const int4v*)&dst[i0]);
                s = __builtin_nontemporal_load((const int4v*)&src[i0]);
                bk0 = d.x >> 8; r0 = atomicAdd(&h[bk0], 1);
                bk1 = d.y >> 8; r1 = atomicAdd(&h[bk1], 1);
                bk2 = d.z >> 8; r2 = atomicAdd(&h[bk2], 1);
                bk3 = d.w >> 8; r3 = atomicAdd(&h[bk3], 1);
            }
            __syncthreads();
            if (h[t])       gb[t] = bs[t] + atomicAdd(&bcursor[t], h[t]);
            if (h[t + 256]) gb[t + 256] = bs[t + 256] + atomicAdd(&bcursor[t + 256], h[t + 256]);
            __syncthreads();
            if (act) {
                pairs[gb[bk0] + r0] = make_int2(s.x, d.x);
                pairs[gb[bk1] + r1] = make_int2(s.y, d.y);
                pairs[gb[bk2] + r2] = make_int2(s.z, d.z);
                pairs[gb[bk3] + r3] = make_int2(s.w, d.w);
            }
            __syncthreads();
        }
    }
    gbar(&bar[1], NB_PRE);

    // ---- Phase C: per-bucket CSR (blocks 0..nbuck-1) ----
    if (blockIdx.x < nbuck) {
        int* bs  = smem;
        int* cnt = smem + 512;
        int* sd  = smem + 768;
        int a = bcnt[t], b = bcnt[t + 256];
        bs[t] = a; bs[t + 256] = b;
        __syncthreads();
        for (int off = 1; off < 512; off <<= 1) {
            int v0 = (t >= off) ? bs[t - off] : 0;
            int v1 = bs[t + 256 - off];
            __syncthreads();
            bs[t] += v0; bs[t + 256] += v1;
            __syncthreads();
        }
        int e0 = bs[t] - a, e1 = bs[t + 256] - b;
        __syncthreads();
        bs[t] = e0; bs[t + 256] = e1;
        __syncthreads();
        int node0 = blockIdx.x << 8;
        int base = bs[blockIdx.x];
        int end  = (blockIdx.x == 511) ? E : bs[blockIdx.x + 1];
        if (blockIdx.x == 0 && t == 0) row_ptr[N] = E;
        cnt[t] = 0;
        __syncthreads();
        for (int i = base + t; i < end; i += 256)
            atomicAdd(&cnt[pairs[i].y & 255], 1);
        __syncthreads();
        int myc = cnt[t];
        sd[t] = myc;
        __syncthreads();
        for (int off = 1; off < 256; off <<= 1) {
            int v = (t >= off) ? sd[t - off] : 0;
            __syncthreads();
            sd[t] += v;
            __syncthreads();
        }
        int ofs = sd[t] - myc;
        int node = node0 + t;
        if (node < N) {
            row_ptr[node] = base + ofs;
            dinv[node] = rsqrtf((float)myc + 1.0f);  // +1 self-loop
        }
        cnt[t] = ofs;
        __syncthreads();
        for (int i = base + t; i < end; i += 256) {
            int2 p = pairs[i];
            int pos = atomicAdd(&cnt[p.y & 255], 1);
            csr_src[base + pos] = p.x;
        }
    }
    gbar(&bar[2], NB_PRE);

    // ---- Phase D: GEMM1 (grid-stride over wave-tiles) ----
    int wv = t >> 6, lane = t & 63;
    for (int tile = blockIdx.x; tile < nbGemm; tile += NB_PRE)
        gemm_body<HID_C, false>(x, wf1, h1, dinv, nullptr, nullptr,
                                N, tile * 4 + wv, lane);
}

// Standalone GEMM (layer 2)
template <int OC, bool BN_IN>
__global__ __launch_bounds__(256) void mfma_gemm_kernel(
    const void* __restrict__ Xv, const ushort* __restrict__ wfrag,
    ushort* __restrict__ Y, const float* __restrict__ dinv,
    const float* __restrict__ sc, const float* __restrict__ sh, int N)
{
    int wave = (blockIdx.x * 256 + threadIdx.x) >> 6;
    gemm_body<OC, BN_IN>(Xv, wfrag, Y, dinv, sc, sh, N, wave, threadIdx.x & 63);
}

// One wave per node, 2x-unrolled gather, bf16 out. NT csr_src reads. (r13)
template <int C>
__global__ __launch_bounds__(256) void aggregate_kernel(
    const ushort* __restrict__ h, const int* __restrict__ row_ptr,
    const int* __restrict__ csr_src, const float* __restrict__ dinv,
    ushort* __restrict__ out, int N)
{
    constexpr int TPN = C / 8;
    constexpr int PAR = 64 / TPN;
    int wid = (blockIdx.x * 256 + threadIdx.x) >> 6;
    if (wid >= N) return;
    int lane = threadIdx.x & 63;
    int part = lane / TPN;
    int c0 = (lane % TPN) * 8;
    float acc[8] = {0.f, 0.f, 0.f, 0.f, 0.f, 0.f, 0.f, 0.f};

    uint4 vself = make_uint4(0u, 0u, 0u, 0u);
    if (part == 0) vself = *(const uint4*)&h[(size_t)wid * C + c0];

    int e = row_ptr[wid] + part;
    int e1 = row_ptr[wid + 1];
    for (; e + PAR < e1; e += 2 * PAR) {
        int s0 = __builtin_nontemporal_load(&csr_src[e]);
        int s1 = __builtin_nontemporal_load(&csr_src[e + PAR]);
        uint4 v0 = *(const uint4*)&h[(size_t)s0 * C + c0];
        uint4 v1 = *(const uint4*)&h[(size_t)s1 * C + c0];
        acc[0] += bf2f((ushort)(v0.x & 0xffff)) + bf2f((ushort)(v1.x & 0xffff));
        acc[1] += bf2f((ushort)(v0.x >> 16))    + bf2f((ushort)(v1.x >> 16));
        acc[2] += bf2f((ushort)(v0.y & 0xffff)) + bf2f((ushort)(v1.y & 0xffff));
        acc[3] += bf2f((ushort)(v0.y >> 16))    + bf2f((ushort)(v1.y >> 16));
        acc[4] += bf2f((ushort)(v0.z & 0xffff)) + bf2f((ushort)(v1.z & 0xffff));
        acc[5] += bf2f((ushort)(v0.z >> 16))    + bf2f((ushort)(v1.z >> 16));
        acc[6] += bf2f((ushort)(v0.w & 0xffff)) + bf2f((ushort)(v1.w & 0xffff));
        acc[7] += bf2f((ushort)(v0.w >> 16))    + bf2f((ushort)(v1.w >> 16));
    }
    if (e < e1) {
        int s = __builtin_nontemporal_load(&csr_src[e]);
        uint4 v = *(const uint4*)&h[(size_t)s * C + c0];
        acc[0] += bf2f((ushort)(v.x & 0xffff));
        acc[1] += bf2f((ushort)(v.x >> 16));
        acc[2] += bf2f((ushort)(v.y & 0xffff));
        acc[3] += bf2f((ushort)(v.y >> 16));
        acc[4] += bf2f((ushort)(v.z & 0xffff));
        acc[5] += bf2f((ushort)(v.z >> 16));
        acc[6] += bf2f((ushort)(v.w & 0xffff));
        acc[7] += bf2f((ushort)(v.w >> 16));
    }
    if (part == 0) {
        acc[0] += bf2f((ushort)(vself.x & 0xffff));
        acc[1] += bf2f((ushort)(vself.x >> 16));
        acc[2] += bf2f((ushort)(vself.y & 0xffff));
        acc[3] += bf2f((ushort)(vself.y >> 16));
        acc[4] += bf2f((ushort)(vself.z & 0xffff));
        acc[5] += bf2f((ushort)(vself.z >> 16));
        acc[6] += bf2f((ushort)(vself.w & 0xffff));
        acc[7] += bf2f((ushort)(vself.w >> 16));
    }
    #pragma unroll
    for (int off = TPN; off < 64; off <<= 1) {
        #pragma unroll
        for (int j = 0; j < 8; ++j)
            acc[j] += __shfl_xor(acc[j], off, 64);
    }
    if (part == 0) {
        float dd = dinv[wid];
        uint4 st;
        #pragma unroll
        for (int j = 0; j < 8; ++j) acc[j] *= dd;
        st.x = (uint)f2bf(acc[0]) | ((uint)f2bf(acc[1]) << 16);
        st.y = (uint)f2bf(acc[2]) | ((uint)f2bf(acc[3]) << 16);
        st.z = (uint)f2bf(acc[4]) | ((uint)f2bf(acc[5]) << 16);
        st.w = (uint)f2bf(acc[6]) | ((uint)f2bf(acc[7]) << 16);
        *(uint4*)&out[(size_t)wid * C + c0] = st;
    }
}

// Per-channel sum & sumsq into NSLAB slabs + last-block BN prep. (r13)
template <int C>
__global__ __launch_bounds__(256) void stats_prep_kernel(
    const ushort* __restrict__ h, float* __restrict__ sums,
    const float* __restrict__ gamma, const float* __restrict__ beta,
    float* __restrict__ sc, float* __restrict__ sh,
    int* __restrict__ ticket, int nblocks, int N)
{
    constexpr int CG = C / 8;
    constexpr int RPB = 256 / CG;
    __shared__ float red[RPB][CG][16];
    __shared__ bool lastblk;
    int tid = threadIdx.x;
    int cg = tid % CG, rg = tid / CG;
    int c0 = cg * 8;
    float s[8] = {0.f,0.f,0.f,0.f,0.f,0.f,0.f,0.f};
    float q[8] = {0.f,0.f,0.f,0.f,0.f,0.f,0.f,0.f};
    for (int r = blockIdx.x * RPB + rg; r < N; r += gridDim.x * RPB) {
        uint4 v = *(const uint4*)&h[(size_t)r * C + c0];
        float f0 = bf2f((ushort)(v.x & 0xffff)), f1 = bf2f((ushort)(v.x >> 16));
        float f2 = bf2f((ushort)(v.y & 0xffff)), f3 = bf2f((ushort)(v.y >> 16));
        float f4 = bf2f((ushort)(v.z & 0xffff)), f5 = bf2f((ushort)(v.z >> 16));
        float f6 = bf2f((ushort)(v.w & 0xffff)), f7 = bf2f((ushort)(v.w >> 16));
        s[0]+=f0; s[1]+=f1; s[2]+=f2; s[3]+=f3; s[4]+=f4; s[5]+=f5; s[6]+=f6; s[7]+=f7;
        q[0]=fmaf(f0,f0,q[0]); q[1]=fmaf(f1,f1,q[1]); q[2]=fmaf(f2,f2,q[2]); q[3]=fmaf(f3,f3,q[3]);
        q[4]=fmaf(f4,f4,q[4]); q[5]=fmaf(f5,f5,q[5]); q[6]=fmaf(f6,f6,q[6]); q[7]=fmaf(f7,f7,q[7]);
    }
    #pragma unroll
    for (int j = 0; j < 8; ++j) { red[rg][cg][j] = s[j]; red[rg][cg][8 + j] = q[j]; }
    __syncthreads();
    float* slab = sums + (size_t)(blockIdx.x & (NSLAB - 1)) * 2 * C;
    if (rg == 0) {
        float a[16];
        #pragma unroll
        for (int i = 0; i < 16; ++i) a[i] = red[0][cg][i];
        for (int r2 = 1; r2 < RPB; ++r2)
            #pragma unroll
            for (int i = 0; i < 16; ++i) a[i] += red[r2][cg][i];
        #pragma unroll
        for (int j = 0; j < 8; ++j) {
            atomicAdd(&slab[c0 + j], a[j]);
            atomicAdd(&slab[C + c0 + j], a[8 + j]);
        }
    }
    __syncthreads();
    if (tid == 0) {
        __threadfence();
        int old = atomicAdd(ticket, 1);
        lastblk = (old == nblocks - 1);
    }
    __syncthreads();
    if (lastblk && tid < C) {
        float sv = 0.f, qv = 0.f;
        #pragma unroll 4
        for (int k = 0; k < NSLAB; ++k) {
            sv += atomicAdd(&sums[(size_t)k * 2 * C + tid], 0.0f);      // coherent
            qv += atomicAdd(&sums[(size_t)k * 2 * C + C + tid], 0.0f);
        }
        float invN = 1.0f / (float)N;
        float mu = sv * invN;
        float var = qv * invN - mu * mu;
        float scl = rsqrtf(var + BN_EPS) * gamma[tid];
        sc[tid] = scl;
        sh[tid] = beta[tid] - mu * scl;
    }
}

// BN2 apply: bf16 in -> f32 out, 8 channels per thread
__global__ void bn_apply_kernel(const ushort* __restrict__ in, float* __restrict__ out,
                                const float* __restrict__ sc, const float* __restrict__ sh,
                                int N)
{
    int total = N * (OUT_C2 / 8);
    int i = blockIdx.x * blockDim.x + threadIdx.x;
    int stride = gridDim.x * blockDim.x;
    for (; i < total; i += stride) {
        int c0 = (i & 7) * 8;
        uint4 v = *(const uint4*)&in[(size_t)i * 8];
        float4 s0 = *(const float4*)&sc[c0];
        float4 s1 = *(const float4*)&sc[c0 + 4];
        float4 h0 = *(const float4*)&sh[c0];
        float4 h1 = *(const float4*)&sh[c0 + 4];
        float4 o0, o1;
        o0.x = fmaf(bf2f((ushort)(v.x & 0xffff)), s0.x, h0.x);
        o0.y = fmaf(bf2f((ushort)(v.x >> 16)),    s0.y, h0.y);
        o0.z = fmaf(bf2f((ushort)(v.y & 0xffff)), s0.z, h0.z);
        o0.w = fmaf(bf2f((ushort)(v.y >> 16)),    s0.w, h0.w);
        o1.x = fmaf(bf2f((ushort)(v.z & 0xffff)), s1.x, h1.x);
        o1.y = fmaf(bf2f((ushort)(v.z >> 16)),    s1.y, h1.y);
        o1.z = fmaf(bf2f((ushort)(v.w & 0xffff)), s1.z, h1.z);
        o1.w = fmaf(bf2f((ushort)(v.w >> 16)),    s1.w, h1.w);
        *(float4*)&out[(size_t)i * 8] = o0;
        *(float4*)&out[(size_t)i * 8 + 4] = o1;
    }
}

extern "C" void kernel_launch(void* const* d_in, const int* in_sizes, int n_in,
                              void* d_out, int out_size, void* d_ws, size_t ws_size,
                              hipStream_t stream) {
    const float* x      = (const float*)d_in[0];
    const int*   ei     = (const int*)d_in[1];
    const float* W1     = (const float*)d_in[2];
    // d_in[3] = b1: cancels in BN1 -> skipped
    const float* gamma1 = (const float*)d_in[4];
    const float* beta1  = (const float*)d_in[5];
    const float* W2     = (const float*)d_in[6];
    // d_in[7] = b2: cancels in BN2 -> skipped
    const float* gamma2 = (const float*)d_in[8];
    const float* beta2  = (const float*)d_in[9];

    const int N = in_sizes[0] / IN_C;   // 100000
    const int E = in_sizes[1] / 2;      // 1600000 (divisible by 4)
    const int* src = ei;
    const int* dst = ei + E;
    const int nTiles = (E + 1023) / 1024;  // 1563
    const int nbuck  = (N + 255) >> 8;     // 391 (<= 512)

    // ws layout (4B words):
    float* ws      = (float*)d_ws;
    float* stats1  = ws;                     // [64][256] = 16384
    float* stats2  = ws + 16384;             // [64][128] = 8192
    float* sc1     = ws + 24576;             // 128
    float* sh1     = ws + 24704;             // 128
    float* sc2     = ws + 24832;             // 64
    float* sh2     = ws + 24896;             // 64
    int*   ticket1 = (int*)(ws + 24960);
    int*   ticket2 = (int*)(ws + 24961);
    int*   bar     = (int*)(ws + 24964);     // 3 barrier counters
    int*   bcnt    = (int*)(ws + 24976);     // 512
    int*   bcursor = (int*)(ws + 25488);     // 512
    float* dinv    = ws + 26000;             // N
    int*   row_ptr = (int*)(dinv + N);       // N+16
    int*   csr_src = row_ptr + N + 16;       // E
    ushort* wfrag1 = (ushort*)(csr_src + E);        // 16384 bf16
    ushort* wfrag2 = wfrag1 + 16384;                // 8192 bf16
    ushort* h1     = wfrag2 + 8192;                 // N*128 bf16 (dinv-prescaled)
    ushort* bufB   = h1 + (size_t)N * HID_C;        // N*128 bf16
    ushort* h2     = bufB + (size_t)N * HID_C;      // N*64 bf16 (dinv-prescaled)
    ushort* agg2b  = h2 + (size_t)N * OUT_C2;       // N*64 bf16
    int2*  pairs   = (int2*)h2;   // alias: E*8B = 12.8MB <= h2+agg2b 25.6MB

    const int nbGemm = (N / 16 + 3) / 4;    // 1563

    // zero slabs/sc/sh/tickets/bars/bcnt/bcursor
    hipMemsetAsync(ws, 0, (size_t)26000 * 4, stream);

    // preproc (count/scan/scatter/csr) + GEMM1, one co-resident dispatch
    preproc_gemm1_kernel<<<NB_PRE, 256, 0, stream>>>(
        src, dst, bcnt, bcursor, pairs, csr_src, row_ptr, dinv, bar,
        W1, W2, wfrag1, wfrag2, x, h1, E, N, nTiles, nbuck, nbGemm);

    aggregate_kernel<HID_C><<<(N + 3) / 4, 256, 0, stream>>>(
        h1, row_ptr, csr_src, dinv, bufB, N);
    stats_prep_kernel<HID_C><<<NB_STATS, 256, 0, stream>>>(
        bufB, stats1, gamma1, beta1, sc1, sh1, ticket1, NB_STATS, N);

    mfma_gemm_kernel<OUT_C2, true><<<nbGemm, 256, 0, stream>>>(
        bufB, wfrag2, h2, dinv, sc1, sh1, N);
    aggregate_kernel<OUT_C2><<<(N + 3) / 4, 256, 0, stream>>>(
        h2, row_ptr, csr_src, dinv, agg2b, N);
    stats_prep_kernel<OUT_C2><<<NB_STATS, 256, 0, stream>>>(
        agg2b, stats2, gamma2, beta2, sc2, sh2, ticket2, NB_STATS, N);

    bn_apply_kernel<<<2048, 256, 0, stream>>>(agg2b, (float*)d_out, sc2, sh2, N);
}

// Round 17
// 333.736 us; speedup vs baseline: 1.8939x; 1.8939x over previous
//
#include <hip/hip_runtime.h>
#include <hip/hip_bf16.h>

// GNN decoder: 2x (GCNConv -> BatchNorm[-> ReLU]) on N=100000 nodes, E=1.6M edges.
// Round 17: REVERT to r13 (best: 334us). Consolidation avenues all falsified:
//  r14: stats fused into 25000-block aggregate -> 6.4M fabric atomics (900us);
//  r15: grid-barrier mega-kernel, RMW-spin -> 394us of barrier serialization;
//  r16: load-spin barrier -> still 432us (structural straggler/phase-serial
//       cost; dispatch boundaries are cheaper than in-kernel barriers here).
// Final structure: 11 dispatches. aggregate<128> at the ~3.7TB/s random-gather
// L3-fabric floor (FETCH = 8 XCDs x full h-buffer, structural for a random
// graph). 64-slab 1024-block stats (r13 contention fix). Bucketed two-phase
// CSR build (r10). dinv-prescaled no-LDS MFMA GEMMs (r3/r4). bf16
// intermediates (r3). CSR gather aggregation (r2). BN bias cancellation (r1).

#define IN_C 128
#define HID_C 128
#define OUT_C2 64
#define BN_EPS 1e-5f
#define NB_STATS 1024
#define NSLAB 64

typedef __attribute__((ext_vector_type(8))) short short8v;
typedef __attribute__((ext_vector_type(4))) float float4v;
typedef __attribute__((ext_vector_type(4))) int int4v;

__device__ inline ushort f2bf(float f) {
    union { float f; unsigned u; } x; x.f = f;
    return (ushort)((x.u + 0x7fffu + ((x.u >> 16) & 1u)) >> 16);  // RNE
}
__device__ inline float bf2f(ushort u) {
    union { unsigned u; float f; } x; x.u = ((unsigned)u) << 16;
    return x.f;
}

// zero slabs/sc/sh/tickets/bcnt/bcursor: ws words [0, 26000)
__global__ void init_kernel(float* __restrict__ ws, int n) {
    int i = blockIdx.x * blockDim.x + threadIdx.x;
    if (i < n) ws[i] = 0.0f;
}

// W[128][OC] f32 -> fragment-ordered bf16
template <int OC>
__device__ inline void wreorder_impl(const float* __restrict__ W,
                                     ushort* __restrict__ wfrag, int t) {
    constexpr int NCT = OC / 16;
    int lane = t & 63;
    int rest = t >> 6;
    int ct = rest % NCT;
    int kk = rest / NCT;
    int col = ct * 16 + (lane & 15);
    int krow = kk * 32 + (lane >> 4) * 8;
    ushort tmp[8];
    #pragma unroll
    for (int e = 0; e < 8; ++e)
        tmp[e] = f2bf(W[(size_t)(krow + e) * OC + col]);
    uint4 st;
    st.x = (uint)tmp[0] | ((uint)tmp[1] << 16);
    st.y = (uint)tmp[2] | ((uint)tmp[3] << 16);
    st.z = (uint)tmp[4] | ((uint)tmp[5] << 16);
    st.w = (uint)tmp[6] | ((uint)tmp[7] << 16);
    *(uint4*)&wfrag[(size_t)t * 8] = st;
}

// Phase A: bucket histogram (LDS) -> global bcnt. Blocks >= nbA do wreorder.
__global__ __launch_bounds__(256) void bucket_count_kernel(
    const int* __restrict__ dst, int* __restrict__ bcnt, int E, int nbA,
    const float* __restrict__ W1, const float* __restrict__ W2,
    ushort* __restrict__ wf1, ushort* __restrict__ wf2)
{
    if (blockIdx.x >= nbA) {
        int b = blockIdx.x - nbA;
        if (b < 8) wreorder_impl<HID_C>(W1, wf1, b * 256 + threadIdx.x);
        else       wreorder_impl<OUT_C2>(W2, wf2, (b - 8) * 256 + threadIdx.x);
        return;
    }
    __shared__ int h[512];
    int t = threadIdx.x;
    h[t] = 0; h[t + 256] = 0;
    __syncthreads();
    int i0 = blockIdx.x * 1024 + t * 4;
    if (i0 < E) {  // E % 4 == 0
        int4v d = __builtin_nontemporal_load((const int4v*)&dst[i0]);
        atomicAdd(&h[d.x >> 8], 1);
        atomicAdd(&h[d.y >> 8], 1);
        atomicAdd(&h[d.z >> 8], 1);
        atomicAdd(&h[d.w >> 8], 1);
    }
    __syncthreads();
    if (h[t])       atomicAdd(&bcnt[t], h[t]);
    if (h[t + 256]) atomicAdd(&bcnt[t + 256], h[t + 256]);
}

// Phase B: scatter (src,dst) into bucket-contiguous pairs[] regions.
__global__ __launch_bounds__(256) void bucket_scatter_kernel(
    const int* __restrict__ src, const int* __restrict__ dst,
    const int* __restrict__ bcnt, int* __restrict__ bcursor,
    int2* __restrict__ pairs, int E)
{
    __shared__ int bs[512];
    __shared__ int h[512];
    __shared__ int gb[512];
    int t = threadIdx.x;
    int a = bcnt[t], b = bcnt[t + 256];
    bs[t] = a; bs[t + 256] = b;
    __syncthreads();
    for (int off = 1; off < 512; off <<= 1) {
        int v0 = (t >= off) ? bs[t - off] : 0;
        int v1 = bs[t + 256 - off];
        __syncthreads();
        bs[t] += v0; bs[t + 256] += v1;
        __syncthreads();
    }
    int e0 = bs[t] - a, e1 = bs[t + 256] - b;
    __syncthreads();
    bs[t] = e0; bs[t + 256] = e1;
    h[t] = 0; h[t + 256] = 0;
    __syncthreads();
    int i0 = blockIdx.x * 1024 + t * 4;
    bool act = i0 < E;
    int4v d, s;
    int bk0 = 0, bk1 = 0, bk2 = 0, bk3 = 0, r0 = 0, r1 = 0, r2 = 0, r3 = 0;
    if (act) {
        d = __builtin_nontemporal_load((const int4v*)&dst[i0]);
        s = __builtin_nontemporal_load((const int4v*)&src[i0]);
        bk0 = d.x >> 8; r0 = atomicAdd(&h[bk0], 1);
        bk1 = d.y >> 8; r1 = atomicAdd(&h[bk1], 1);
        bk2 = d.z >> 8; r2 = atomicAdd(&h[bk2], 1);
        bk3 = d.w >> 8; r3 = atomicAdd(&h[bk3], 1);
    }
    __syncthreads();
    if (h[t])       gb[t] = bs[t] + atomicAdd(&bcursor[t], h[t]);
    if (h[t + 256]) gb[t + 256] = bs[t + 256] + atomicAdd(&bcursor[t + 256], h[t + 256]);
    __syncthreads();
    if (act) {
        pairs[gb[bk0] + r0] = make_int2(s.x, d.x);
        pairs[gb[bk1] + r1] = make_int2(s.y, d.y);
        pairs[gb[bk2] + r2] = make_int2(s.z, d.z);
        pairs[gb[bk3] + r3] = make_int2(s.w, d.w);
    }
}

// Phase C: one block per bucket (256 nodes, ~4K edges, L2-resident).
__global__ __launch_bounds__(256) void bucket_csr_kernel(
    const int2* __restrict__ pairs, const int* __restrict__ bcnt,
    int* __restrict__ csr_src, int* __restrict__ row_ptr,
    float* __restrict__ dinv, int E, int N)
{
    __shared__ int bs[512];
    __shared__ int cnt[256];
    __shared__ int sd[256];
    int t = threadIdx.x;
    int a = bcnt[t], b = bcnt[t + 256];
    bs[t] = a; bs[t + 256] = b;
    __syncthreads();
    for (int off = 1; off < 512; off <<= 1) {
        int v0 = (t >= off) ? bs[t - off] : 0;
        int v1 = bs[t + 256 - off];
        __syncthreads();
        bs[t] += v0; bs[t + 256] += v1;
        __syncthreads();
    }
    int e0 = bs[t] - a, e1 = bs[t + 256] - b;
    __syncthreads();
    bs[t] = e0; bs[t + 256] = e1;
    __syncthreads();
    int node0 = blockIdx.x << 8;
    int base = bs[blockIdx.x];
    int end  = (blockIdx.x == 511) ? E : bs[blockIdx.x + 1];
    if (blockIdx.x == 0 && t == 0) row_ptr[N] = E;
    cnt[t] = 0;
    __syncthreads();
    for (int i = base + t; i < end; i += 256)
        atomicAdd(&cnt[pairs[i].y & 255], 1);
    __syncthreads();
    int myc = cnt[t];
    sd[t] = myc;
    __syncthreads();
    for (int off = 1; off < 256; off <<= 1) {
        int v = (t >= off) ? sd[t - off] : 0;
        __syncthreads();
        sd[t] += v;
        __syncthreads();
    }
    int ofs = sd[t] - myc;  // exclusive
    int node = node0 + t;
    if (node < N) {
        row_ptr[node] = base + ofs;
        dinv[node] = rsqrtf((float)myc + 1.0f);  // +1 self-loop
    }
    cnt[t] = ofs;           // becomes intra-bucket cursor
    __syncthreads();
    for (int i = base + t; i < end; i += 256) {
        int2 p = pairs[i];
        int pos = atomicAdd(&cnt[p.y & 255], 1);
        csr_src[base + pos] = p.x;
    }
}

// MFMA GEMM: Y[N][OC] bf16 = dinv[row] * (A @ W). No LDS. NT loads for f32 A.
template <int OC, bool BN_IN>
__global__ __launch_bounds__(256) void mfma_gemm_kernel(
    const void* __restrict__ Xv, const ushort* __restrict__ wfrag,
    ushort* __restrict__ Y, const float* __restrict__ dinv,
    const float* __restrict__ sc, const float* __restrict__ sh, int N)
{
    constexpr int NCT = OC / 16;
    int wave = (blockIdx.x * 256 + threadIdx.x) >> 6;
    int lane = threadIdx.x & 63;
    int row16 = wave * 16;
    if (row16 >= N) return;
    int r = lane & 15;
    int g = lane >> 4;
    int row = row16 + r;

    float4v acc[NCT];
    #pragma unroll
    for (int ct = 0; ct < NCT; ++ct) acc[ct] = (float4v){0.f, 0.f, 0.f, 0.f};

    const short8v* wf = (const short8v*)wfrag;

    #pragma unroll
    for (int kk = 0; kk < 4; ++kk) {
        int k0 = kk * 32 + g * 8;
        short8v a;
        if constexpr (!BN_IN) {
            const float* xp = (const float*)Xv + (size_t)row * 128 + k0;
            float4v x0 = __builtin_nontemporal_load((const float4v*)xp);
            float4v x1 = __builtin_nontemporal_load((const float4v*)(xp + 4));
            a[0] = (short)f2bf(x0[0]); a[1] = (short)f2bf(x0[1]);
            a[2] = (short)f2bf(x0[2]); a[3] = (short)f2bf(x0[3]);
            a[4] = (short)f2bf(x1[0]); a[5] = (short)f2bf(x1[1]);
            a[6] = (short)f2bf(x1[2]); a[7] = (short)f2bf(x1[3]);
        } else {
            const ushort* xp = (const ushort*)Xv + (size_t)row * 128 + k0;
            uint4 v = *(const uint4*)xp;
            float4 s0 = *(const float4*)&sc[k0];
            float4 s1 = *(const float4*)&sc[k0 + 4];
            float4 h0 = *(const float4*)&sh[k0];
            float4 h1 = *(const float4*)&sh[k0 + 4];
            a[0] = (short)f2bf(fmaxf(fmaf(bf2f((ushort)(v.x & 0xffff)), s0.x, h0.x), 0.f));
            a[1] = (short)f2bf(fmaxf(fmaf(bf2f((ushort)(v.x >> 16)),    s0.y, h0.y), 0.f));
            a[2] = (short)f2bf(fmaxf(fmaf(bf2f((ushort)(v.y & 0xffff)), s0.z, h0.z), 0.f));
            a[3] = (short)f2bf(fmaxf(fmaf(bf2f((ushort)(v.y >> 16)),    s0.w, h0.w), 0.f));
            a[4] = (short)f2bf(fmaxf(fmaf(bf2f((ushort)(v.z & 0xffff)), s1.x, h1.x), 0.f));
            a[5] = (short)f2bf(fmaxf(fmaf(bf2f((ushort)(v.z >> 16)),    s1.y, h1.y), 0.f));
            a[6] = (short)f2bf(fmaxf(fmaf(bf2f((ushort)(v.w & 0xffff)), s1.z, h1.z), 0.f));
            a[7] = (short)f2bf(fmaxf(fmaf(bf2f((ushort)(v.w >> 16)),    s1.w, h1.w), 0.f));
        }
        #pragma unroll
        for (int ct = 0; ct < NCT; ++ct) {
            short8v b = wf[((size_t)(kk * NCT + ct)) * 64 + lane];
            acc[ct] = __builtin_amdgcn_mfma_f32_16x16x32_bf16(a, b, acc[ct], 0, 0, 0);
        }
    }
    float di[4];
    #pragma unroll
    for (int i = 0; i < 4; ++i) di[i] = dinv[row16 + g * 4 + i];
    #pragma unroll
    for (int ct = 0; ct < NCT; ++ct) {
        #pragma unroll
        for (int i = 0; i < 4; ++i) {
            int orow = row16 + g * 4 + i;
            Y[(size_t)orow * OC + ct * 16 + r] = f2bf(acc[ct][i] * di[i]);
        }
    }
}

// One wave per node, 2x-unrolled gather, bf16 out. NT csr_src reads.
template <int C>
__global__ __launch_bounds__(256) void aggregate_kernel(
    const ushort* __restrict__ h, const int* __restrict__ row_ptr,
    const int* __restrict__ csr_src, const float* __restrict__ dinv,
    ushort* __restrict__ out, int N)
{
    constexpr int TPN = C / 8;
    constexpr int PAR = 64 / TPN;
    int wid = (blockIdx.x * 256 + threadIdx.x) >> 6;
    if (wid >= N) return;
    int lane = threadIdx.x & 63;
    int part = lane / TPN;
    int c0 = (lane % TPN) * 8;
    float acc[8] = {0.f, 0.f, 0.f, 0.f, 0.f, 0.f, 0.f, 0.f};

    uint4 vself = make_uint4(0u, 0u, 0u, 0u);
    if (part == 0) vself = *(const uint4*)&h[(size_t)wid * C + c0];

    int e = row_ptr[wid] + part;
    int e1 = row_ptr[wid + 1];
    for (; e + PAR < e1; e += 2 * PAR) {
        int s0 = __builtin_nontemporal_load(&csr_src[e]);
        int s1 = __builtin_nontemporal_load(&csr_src[e + PAR]);
        uint4 v0 = *(const uint4*)&h[(size_t)s0 * C + c0];
        uint4 v1 = *(const uint4*)&h[(size_t)s1 * C + c0];
        acc[0] += bf2f((ushort)(v0.x & 0xffff)) + bf2f((ushort)(v1.x & 0xffff));
        acc[1] += bf2f((ushort)(v0.x >> 16))    + bf2f((ushort)(v1.x >> 16));
        acc[2] += bf2f((ushort)(v0.y & 0xffff)) + bf2f((ushort)(v1.y & 0xffff));
        acc[3] += bf2f((ushort)(v0.y >> 16))    + bf2f((ushort)(v1.y >> 16));
        acc[4] += bf2f((ushort)(v0.z & 0xffff)) + bf2f((ushort)(v1.z & 0xffff));
        acc[5] += bf2f((ushort)(v0.z >> 16))    + bf2f((ushort)(v1.z >> 16));
        acc[6] += bf2f((ushort)(v0.w & 0xffff)) + bf2f((ushort)(v1.w & 0xffff));
        acc[7] += bf2f((ushort)(v0.w >> 16))    + bf2f((ushort)(v1.w >> 16));
    }
    if (e < e1) {
        int s = __builtin_nontemporal_load(&csr_src[e]);
        uint4 v = *(const uint4*)&h[(size_t)s * C + c0];
        acc[0] += bf2f((ushort)(v.x & 0xffff));
        acc[1] += bf2f((ushort)(v.x >> 16));
        acc[2] += bf2f((ushort)(v.y & 0xffff));
        acc[3] += bf2f((ushort)(v.y >> 16));
        acc[4] += bf2f((ushort)(v.z & 0xffff));
        acc[5] += bf2f((ushort)(v.z >> 16));
        acc[6] += bf2f((ushort)(v.w & 0xffff));
        acc[7] += bf2f((ushort)(v.w >> 16));
    }
    if (part == 0) {
        acc[0] += bf2f((ushort)(vself.x & 0xffff));
        acc[1] += bf2f((ushort)(vself.x >> 16));
        acc[2] += bf2f((ushort)(vself.y & 0xffff));
        acc[3] += bf2f((ushort)(vself.y >> 16));
        acc[4] += bf2f((ushort)(vself.z & 0xffff));
        acc[5] += bf2f((ushort)(vself.z >> 16));
        acc[6] += bf2f((ushort)(vself.w & 0xffff));
        acc[7] += bf2f((ushort)(vself.w >> 16));
    }
    #pragma unroll
    for (int off = TPN; off < 64; off <<= 1) {
        #pragma unroll
        for (int j = 0; j < 8; ++j)
            acc[j] += __shfl_xor(acc[j], off, 64);
    }
    if (part == 0) {
        float dd = dinv[wid];
        uint4 st;
        #pragma unroll
        for (int j = 0; j < 8; ++j) acc[j] *= dd;
        st.x = (uint)f2bf(acc[0]) | ((uint)f2bf(acc[1]) << 16);
        st.y = (uint)f2bf(acc[2]) | ((uint)f2bf(acc[3]) << 16);
        st.z = (uint)f2bf(acc[4]) | ((uint)f2bf(acc[5]) << 16);
        st.w = (uint)f2bf(acc[6]) | ((uint)f2bf(acc[7]) << 16);
        *(uint4*)&out[(size_t)wid * C + c0] = st;
    }
}

// Per-channel sum & sumsq over bf16 rows into NSLAB slabs + last-block BN prep.
template <int C>
__global__ __launch_bounds__(256) void stats_prep_kernel(
    const ushort* __restrict__ h, float* __restrict__ sums,
    const float* __restrict__ gamma, const float* __restrict__ beta,
    float* __restrict__ sc, float* __restrict__ sh,
    int* __restrict__ ticket, int nblocks, int N)
{
    constexpr int CG = C / 8;
    constexpr int RPB = 256 / CG;
    __shared__ float red[RPB][CG][16];
    __shared__ bool lastblk;
    int tid = threadIdx.x;
    int cg = tid % CG, rg = tid / CG;
    int c0 = cg * 8;
    float s[8] = {0.f,0.f,0.f,0.f,0.f,0.f,0.f,0.f};
    float q[8] = {0.f,0.f,0.f,0.f,0.f,0.f,0.f,0.f};
    for (int r = blockIdx.x * RPB + rg; r < N; r += gridDim.x * RPB) {
        uint4 v = *(const uint4*)&h[(size_t)r * C + c0];
        float f0 = bf2f((ushort)(v.x & 0xffff)), f1 = bf2f((ushort)(v.x >> 16));
        float f2 = bf2f((ushort)(v.y & 0xffff)), f3 = bf2f((ushort)(v.y >> 16));
        float f4 = bf2f((ushort)(v.z & 0xffff)), f5 = bf2f((ushort)(v.z >> 16));
        float f6 = bf2f((ushort)(v.w & 0xffff)), f7 = bf2f((ushort)(v.w >> 16));
        s[0]+=f0; s[1]+=f1; s[2]+=f2; s[3]+=f3; s[4]+=f4; s[5]+=f5; s[6]+=f6; s[7]+=f7;
        q[0]=fmaf(f0,f0,q[0]); q[1]=fmaf(f1,f1,q[1]); q[2]=fmaf(f2,f2,q[2]); q[3]=fmaf(f3,f3,q[3]);
        q[4]=fmaf(f4,f4,q[4]); q[5]=fmaf(f5,f5,q[5]); q[6]=fmaf(f6,f6,q[6]); q[7]=fmaf(f7,f7,q[7]);
    }
    #pragma unroll
    for (int j = 0; j < 8; ++j) { red[rg][cg][j] = s[j]; red[rg][cg][8 + j] = q[j]; }
    __syncthreads();
    float* slab = sums + (size_t)(blockIdx.x & (NSLAB - 1)) * 2 * C;
    if (rg == 0) {
        float a[16];
        #pragma unroll
        for (int i = 0; i < 16; ++i) a[i] = red[0][cg][i];
        for (int r2 = 1; r2 < RPB; ++r2)
            #pragma unroll
            for (int i = 0; i < 16; ++i) a[i] += red[r2][cg][i];
        #pragma unroll
        for (int j = 0; j < 8; ++j) {
            atomicAdd(&slab[c0 + j], a[j]);
            atomicAdd(&slab[C + c0 + j], a[8 + j]);
        }
    }
    __syncthreads();
    if (tid == 0) {
        __threadfence();
        int old = atomicAdd(ticket, 1);
        lastblk = (old == nblocks - 1);
    }
    __syncthreads();
    if (lastblk && tid < C) {
        float sv = 0.f, qv = 0.f;
        #pragma unroll 4
        for (int k = 0; k < NSLAB; ++k) {
            sv += atomicAdd(&sums[(size_t)k * 2 * C + tid], 0.0f);      // coherent
            qv += atomicAdd(&sums[(size_t)k * 2 * C + C + tid], 0.0f);
        }
        float invN = 1.0f / (float)N;
        float mu = sv * invN;
        float var = qv * invN - mu * mu;
        float scl = rsqrtf(var + BN_EPS) * gamma[tid];
        sc[tid] = scl;
        sh[tid] = beta[tid] - mu * scl;
    }
}

// BN2 apply: bf16 in -> f32 out, 8 channels per thread
__global__ void bn_apply_kernel(const ushort* __restrict__ in, float* __restrict__ out,
                                const float* __restrict__ sc, const float* __restrict__ sh,
                                int N)
{
    int total = N * (OUT_C2 / 8);
    int i = blockIdx.x * blockDim.x + threadIdx.x;
    int stride = gridDim.x * blockDim.x;
    for (; i < total; i += stride) {
        int c0 = (i & 7) * 8;
        uint4 v = *(const uint4*)&in[(size_t)i * 8];
        float4 s0 = *(const float4*)&sc[c0];
        float4 s1 = *(const float4*)&sc[c0 + 4];
        float4 h0 = *(const float4*)&sh[c0];
        float4 h1 = *(const float4*)&sh[c0 + 4];
        float4 o0, o1;
        o0.x = fmaf(bf2f((ushort)(v.x & 0xffff)), s0.x, h0.x);
        o0.y = fmaf(bf2f((ushort)(v.x >> 16)),    s0.y, h0.y);
        o0.z = fmaf(bf2f((ushort)(v.y & 0xffff)), s0.z, h0.z);
        o0.w = fmaf(bf2f((ushort)(v.y >> 16)),    s0.w, h0.w);
        o1.x = fmaf(bf2f((ushort)(v.z & 0xffff)), s1.x, h1.x);
        o1.y = fmaf(bf2f((ushort)(v.z >> 16)),    s1.y, h1.y);
        o1.z = fmaf(bf2f((ushort)(v.w & 0xffff)), s1.z, h1.z);
        o1.w = fmaf(bf2f((ushort)(v.w >> 16)),    s1.w, h1.w);
        *(float4*)&out[(size_t)i * 8] = o0;
        *(float4*)&out[(size_t)i * 8 + 4] = o1;
    }
}

extern "C" void kernel_launch(void* const* d_in, const int* in_sizes, int n_in,
                              void* d_out, int out_size, void* d_ws, size_t ws_size,
                              hipStream_t stream) {
    const float* x      = (const float*)d_in[0];
    const int*   ei     = (const int*)d_in[1];
    const float* W1     = (const float*)d_in[2];
    // d_in[3] = b1: cancels in BN1 -> skipped
    const float* gamma1 = (const float*)d_in[4];
    const float* beta1  = (const float*)d_in[5];
    const float* W2     = (const float*)d_in[6];
    // d_in[7] = b2: cancels in BN2 -> skipped
    const float* gamma2 = (const float*)d_in[8];
    const float* beta2  = (const float*)d_in[9];

    const int N = in_sizes[0] / IN_C;   // 100000 (divisible by 16)
    const int E = in_sizes[1] / 2;      // 1600000 (divisible by 4)
    const int* src = ei;
    const int* dst = ei + E;
    const int nbA   = (E + 1023) / 1024;   // 1563
    const int nbuck = (N + 255) >> 8;      // 391 (<= 512)

    // ws layout (4B words):
    float* ws      = (float*)d_ws;
    float* stats1  = ws;                     // [NSLAB][256] = 16384
    float* stats2  = ws + 16384;             // [NSLAB][128] = 8192
    float* sc1     = ws + 24576;             // 128
    float* sh1     = ws + 24704;             // 128
    float* sc2     = ws + 24832;             // 64
    float* sh2     = ws + 24896;             // 64
    int*   ticket1 = (int*)(ws + 24960);
    int*   ticket2 = (int*)(ws + 24961);
    int*   bcnt    = (int*)(ws + 24976);     // 512
    int*   bcursor = (int*)(ws + 25488);     // 512
    float* dinv    = ws + 26000;             // N (26000*4 % 16 == 0)
    int*   row_ptr = (int*)(dinv + N);       // N+16
    int*   csr_src = row_ptr + N + 16;       // E
    ushort* wfrag1 = (ushort*)(csr_src + E);        // 16384 bf16
    ushort* wfrag2 = wfrag1 + 16384;                // 8192 bf16
    ushort* h1     = wfrag2 + 8192;                 // N*128 bf16 (dinv-prescaled)
    ushort* bufB   = h1 + (size_t)N * HID_C;        // N*128 bf16
    ushort* h2     = bufB + (size_t)N * HID_C;      // N*64 bf16 (dinv-prescaled)
    ushort* agg2b  = h2 + (size_t)N * OUT_C2;       // N*64 bf16
    int2*  pairs   = (int2*)h2;   // alias: E*8B = 12.8MB <= h2+agg2b 25.6MB; dead before gemm2

    const int nbGemm = (N / 16 + 3) / 4;    // 1563
    const int initN = 26000;

    init_kernel<<<(initN + 255) / 256, 256, 0, stream>>>(ws, initN);
    bucket_count_kernel<<<nbA + 12, 256, 0, stream>>>(dst, bcnt, E, nbA,
                                                      W1, W2, wfrag1, wfrag2);
    bucket_scatter_kernel<<<nbA, 256, 0, stream>>>(src, dst, bcnt, bcursor, pairs, E);
    bucket_csr_kernel<<<nbuck, 256, 0, stream>>>(pairs, bcnt, csr_src, row_ptr,
                                                 dinv, E, N);

    // Layer 1
    mfma_gemm_kernel<HID_C, false><<<nbGemm, 256, 0, stream>>>(
        x, wfrag1, h1, dinv, nullptr, nullptr, N);
    aggregate_kernel<HID_C><<<(N + 3) / 4, 256, 0, stream>>>(
        h1, row_ptr, csr_src, dinv, bufB, N);
    stats_prep_kernel<HID_C><<<NB_STATS, 256, 0, stream>>>(
        bufB, stats1, gamma1, beta1, sc1, sh1, ticket1, NB_STATS, N);

    // Layer 2
    mfma_gemm_kernel<OUT_C2, true><<<nbGemm, 256, 0, stream>>>(
        bufB, wfrag2, h2, dinv, sc1, sh1, N);
    aggregate_kernel<OUT_C2><<<(N + 3) / 4, 256, 0, stream>>>(
        h2, row_ptr, csr_src, dinv, agg2b, N);
    stats_prep_kernel<OUT_C2><<<NB_STATS, 256, 0, stream>>>(
        agg2b, stats2, gamma2, beta2, sc2, sh2, ticket2, NB_STATS, N);

    bn_apply_kernel<<<2048, 256, 0, stream>>>(agg2b, (float*)d_out, sc2, sh2, N);
}